// Round 1
// baseline (1100.934 us; speedup 1.0000x reference)
//
#include <hip/hip_runtime.h>
#include <hip/hip_bf16.h>
#include <stdint.h>

#define NUM_CLASS 100000
#define CPAD      100096      // padded to multiple of 256
#define EMB       512
#define NROW      1024

#define BM 128
#define BN 256
#define BK 64                 // ushorts of K per tile
#define NBN 391               // CPAD / BN
#define NBM 8                 // NROW / BM

typedef __bf16 bf16x8 __attribute__((ext_vector_type(8)));
typedef float  f32x4  __attribute__((ext_vector_type(4)));

// ---- ws layout (bytes) ----
#define WS_FTL  256
#define WS_FTL2 4352
#define WS_A    8704
#define WS_B    1057280

__device__ inline unsigned short f2bf(float x) {
    uint32_t u = __builtin_bit_cast(uint32_t, x);
    uint32_t r = u + 0x7FFFu + ((u >> 16) & 1u);   // RNE, inputs are finite
    return (unsigned short)(r >> 16);
}
__device__ inline unsigned int pack2(float a, float b) {
    return (unsigned int)f2bf(a) | ((unsigned int)f2bf(b) << 16);
}

// async global->LDS, 16 B per lane; LDS dst is wave-uniform base + lane*16
__device__ __forceinline__ void gld16(const unsigned short* g, unsigned short* l) {
    __builtin_amdgcn_global_load_lds(
        (const __attribute__((address_space(1))) unsigned int*)g,
        (__attribute__((address_space(3))) unsigned int*)l,
        16, 0, 0);
}

// ---- normalize logits rows -> bf16 A ----
__global__ __launch_bounds__(256) void prep_a(const float* __restrict__ logits,
                                              unsigned short* __restrict__ A) {
    int wave = threadIdx.x >> 6, lane = threadIdx.x & 63;
    int row = blockIdx.x * 4 + wave;
    const float4* src = (const float4*)(logits + (size_t)row * EMB + lane * 8);
    float4 a = src[0], b = src[1];
    float ss = a.x*a.x + a.y*a.y + a.z*a.z + a.w*a.w
             + b.x*b.x + b.y*b.y + b.z*b.z + b.w*b.w;
    for (int off = 32; off; off >>= 1) ss += __shfl_xor(ss, off, 64);
    float rs = rsqrtf(ss + 1e-12f);
    uint4 o;
    o.x = pack2(a.x*rs, a.y*rs); o.y = pack2(a.z*rs, a.w*rs);
    o.z = pack2(b.x*rs, b.y*rs); o.w = pack2(b.z*rs, b.w*rs);
    *(uint4*)(A + (size_t)row * EMB + lane * 8) = o;
}

// ---- normalize weight rows -> bf16 B (padded rows zero) ----
__global__ __launch_bounds__(256) void prep_b(const float* __restrict__ w,
                                              unsigned short* __restrict__ B) {
    int wave = threadIdx.x >> 6, lane = threadIdx.x & 63;
    int row = blockIdx.x * 4 + wave;
    uint4 o = {0u, 0u, 0u, 0u};
    if (row < NUM_CLASS) {
        const float4* src = (const float4*)(w + (size_t)row * EMB + lane * 8);
        float4 a = src[0], b = src[1];
        float ss = a.x*a.x + a.y*a.y + a.z*a.z + a.w*a.w
                 + b.x*b.x + b.y*b.y + b.z*b.z + b.w*b.w;
        for (int off = 32; off; off >>= 1) ss += __shfl_xor(ss, off, 64);
        float rs = rsqrtf(ss + 1e-12f);
        o.x = pack2(a.x*rs, a.y*rs); o.y = pack2(a.z*rs, a.w*rs);
        o.z = pack2(b.x*rs, b.y*rs); o.w = pack2(b.z*rs, b.w*rs);
    }
    *(uint4*)(B + (size_t)row * EMB + lane * 8) = o;
}

// ---- per-row target cosine + margin thresholds (fp32), zero counter ----
__global__ __launch_bounds__(64) void prep_rows(const float* __restrict__ logits,
                                                const float* __restrict__ w,
                                                const int* __restrict__ labels,
                                                float* __restrict__ ftl,
                                                float* __restrict__ ftl2,
                                                unsigned int* __restrict__ cnt) {
    int row = blockIdx.x, lane = threadIdx.x;
    if (row == 0 && lane == 0) *cnt = 0u;
    int lab = labels[row];
    const float4* lp = (const float4*)(logits + (size_t)row * EMB + lane * 8);
    const float4* wp = (const float4*)(w + (size_t)lab * EMB + lane * 8);
    float4 l0 = lp[0], l1 = lp[1], w0 = wp[0], w1 = wp[1];
    float sl = l0.x*l0.x + l0.y*l0.y + l0.z*l0.z + l0.w*l0.w
             + l1.x*l1.x + l1.y*l1.y + l1.z*l1.z + l1.w*l1.w;
    float sw = w0.x*w0.x + w0.y*w0.y + w0.z*w0.z + w0.w*w0.w
             + w1.x*w1.x + w1.y*w1.y + w1.z*w1.z + w1.w*w1.w;
    float d  = l0.x*w0.x + l0.y*w0.y + l0.z*w0.z + l0.w*w0.w
             + l1.x*w1.x + l1.y*w1.y + l1.z*w1.z + l1.w*w1.w;
    for (int off = 32; off; off >>= 1) {
        sl += __shfl_xor(sl, off, 64);
        sw += __shfl_xor(sw, off, 64);
        d  += __shfl_xor(d,  off, 64);
    }
    if (lane == 0) {
        float tgt = d * rsqrtf(sl + 1e-12f) * rsqrtf(sw + 1e-12f);
        tgt = fminf(1.0f, fmaxf(-1.0f, tgt));
        const float cos_m  = 0.8775825618903728f;
        const float sin_m  = 0.479425538604203f;
        const float theta  = -0.8775825618903728f;
        const float sinmm  = 0.2397127693021015f;
        const float cos_m_ = 0.9800665778412416f;
        const float sin_m_ = 0.19866933079506122f;
        const float sinmm_ = -0.03973386615901225f;
        float st   = sqrtf(fmaxf(0.0f, 1.0f - tgt * tgt));
        float ctm  = tgt * cos_m  - st * sin_m;
        float ctm_ = tgt * cos_m_ - st * sin_m_;
        ftl[row]  = (tgt > theta)    ? ctm  : (tgt - sinmm);
        ftl2[row] = (tgt <= cos_m_)  ? ctm_ : (tgt + sinmm_);
    }
}

// ---- bf16 MFMA GEMM: cos = A * B^T, write clipped cos, count ----
// 128x256 tile per block, 4 waves (2M x 2N, 64x128 each), acc[4][8].
// LDS layout is XOR-swizzled (slot ^= row&7) via pre-swizzled GLOBAL source
// (gld16 dst must stay linear) + matching XOR on the ds_read side.
// XCD-bijective remap: 3128 blocks = 8 XCDs * 391; the 8 bm-tiles sharing a
// B-tile land contiguously on one XCD -> B fetched ~once per L2.
__global__ __launch_bounds__(256) void gemm_count(const unsigned short* __restrict__ A,
                                                  const unsigned short* __restrict__ B,
                                                  const float* __restrict__ ftl,
                                                  float* __restrict__ out,
                                                  unsigned int* __restrict__ cnt) {
    __shared__ __align__(16) unsigned short lA[BM * BK];   // 16 KB
    __shared__ __align__(16) unsigned short lB[BN * BK];   // 32 KB
    int tid = threadIdx.x;
    int wave = tid >> 6, lane = tid & 63;
    int wm = wave >> 1, wn = wave & 1;
    int quad = lane >> 4, l16 = lane & 15;
    int sw = l16 & 7;                    // read-side swizzle key (= row&7)

    // XCD-aware bijective remap (grid 3128 = 8 * 391, r=0 clean case)
    int f  = blockIdx.x;
    int wg = (f & 7) * NBN + (f >> 3);
    int bm = wg & 7;                     // fast: 8 row-tiles share one B-tile
    int bn = wg >> 3;

    f32x4 acc[4][8] = {};

    int srow  = tid >> 3;                // 0..31
    int sslot = tid & 7;                 // linear LDS 16B slot within row
    int sg    = sslot ^ (srow & 7);      // pre-swizzled global slot
    const unsigned short* a_src = A + ((size_t)(bm * BM + srow)) * EMB + sg * 8;
    const unsigned short* b_src = B + ((size_t)(bn * BN + srow)) * EMB + sg * 8;
    unsigned short* a_dst = &lA[tid * 8];   // linear: wave base + lane*16B
    unsigned short* b_dst = &lB[tid * 8];

#pragma unroll 1
    for (int kk = 0; kk < EMB / BK; ++kk) {
        int k0 = kk * BK;
#pragma unroll
        for (int r = 0; r < 4; ++r)
            gld16(a_src + (size_t)r * 32 * EMB + k0, a_dst + r * 2048);
#pragma unroll
        for (int r = 0; r < 8; ++r)
            gld16(b_src + (size_t)r * 32 * EMB + k0, b_dst + r * 2048);
        __syncthreads();   // drains vmcnt: staged data visible
#pragma unroll
        for (int ks = 0; ks < 2; ++ks) {
            bf16x8 af[4], bfr[8];
#pragma unroll
            for (int i = 0; i < 4; ++i) {
                int ar = wm * 64 + i * 16 + l16;               // ar&7 == sw
                af[i]  = *(const bf16x8*)&lA[ar * BK + (((ks * 4 + quad) ^ sw) << 3)];
            }
#pragma unroll
            for (int j = 0; j < 8; ++j) {
                int br = wn * 128 + j * 16 + l16;              // br&7 == sw
                bfr[j] = *(const bf16x8*)&lB[br * BK + (((ks * 4 + quad) ^ sw) << 3)];
            }
#pragma unroll
            for (int i = 0; i < 4; ++i)
#pragma unroll
                for (int j = 0; j < 8; ++j)
                    acc[i][j] = __builtin_amdgcn_mfma_f32_16x16x32_bf16(af[i], bfr[j], acc[i][j], 0, 0, 0);
        }
        __syncthreads();   // all reads done before next overwrite
    }

    int local = 0;
#pragma unroll
    for (int i = 0; i < 4; ++i) {
        int row0 = bm * BM + wm * 64 + i * 16 + quad * 4;
        float f0 = ftl[row0], f1 = ftl[row0 + 1], f2 = ftl[row0 + 2], f3 = ftl[row0 + 3];
#pragma unroll
        for (int j = 0; j < 8; ++j) {
            int col = bn * BN + wn * 128 + j * 16 + l16;
            bool cv = col < NUM_CLASS;
#pragma unroll
            for (int r = 0; r < 4; ++r) {
                float c = acc[i][j][r];
                c = fminf(1.0f, fmaxf(-1.0f, c));
                if (cv) {
                    float fr = (r == 0) ? f0 : (r == 1) ? f1 : (r == 2) ? f2 : f3;
                    local += (c > fr) ? 1 : 0;
                    out[(size_t)(row0 + r) * NUM_CLASS + col] = c;
                }
            }
        }
    }
    for (int off = 32; off; off >>= 1) local += __shfl_down(local, off, 64);
    if (lane == 0) atomicAdd(cnt, (unsigned int)local);
}

// ---- elementwise epilogue: masks, noise scale, diagonal set, *S ----
// grid 4096 = 1024 rows * 4 quarter-blocks; row-uniform per block so
// ftl/ftl2/label are scalar loads and no per-element division is needed.
__global__ __launch_bounds__(256) void apply_k(float* __restrict__ out,
                                               const float* __restrict__ ftl,
                                               const float* __restrict__ ftl2,
                                               const int* __restrict__ labels,
                                               const unsigned int* __restrict__ cnt) {
    int row     = blockIdx.x >> 2;
    int quarter = blockIdx.x & 3;
    float h   = (float)(*cnt);
    float msm = ((2900.0f - h) / 2900.0f) * 0.01f;
    float t   = 1.0f - msm / 0.7f;
    float ns  = t * t;
    float fv  = ftl[row], f2v = ftl2[row];
    int   lab = labels[row];
    float4* base = (float4*)(out + (size_t)row * NUM_CLASS);
    int c4end = (quarter + 1) * 6250;                 // 25000 float4 per row
    for (int c4 = quarter * 6250 + (int)threadIdx.x; c4 < c4end; c4 += 256) {
        float4 v = base[c4];
        float r[4] = {v.x, v.y, v.z, v.w};
        int col = c4 * 4;
#pragma unroll
        for (int q = 0; q < 4; ++q) {
            float c = r[q];
            float o = (c > fv) ? c * 1.2f : c;        // hard margin: *(T+1)
            if (c > f2v) o = fmaxf(c * ns, 1e-30f);   // noise branch overrides
            if (col + q == lab) o = fv;               // diagonal set
            r[q] = o * 64.0f;                          // *S
        }
        base[c4] = make_float4(r[0], r[1], r[2], r[3]);
    }
}

extern "C" void kernel_launch(void* const* d_in, const int* in_sizes, int n_in,
                              void* d_out, int out_size, void* d_ws, size_t ws_size,
                              hipStream_t stream) {
    const float* logits = (const float*)d_in[0];
    const int*   labels = (const int*)d_in[1];
    const float* weight = (const float*)d_in[2];
    char* ws = (char*)d_ws;
    unsigned int*  cnt  = (unsigned int*)ws;
    float*         ftl  = (float*)(ws + WS_FTL);
    float*         ftl2 = (float*)(ws + WS_FTL2);
    unsigned short* A   = (unsigned short*)(ws + WS_A);
    unsigned short* B   = (unsigned short*)(ws + WS_B);
    float* out = (float*)d_out;

    prep_a<<<NROW / 4, 256, 0, stream>>>(logits, A);
    prep_b<<<CPAD / 4, 256, 0, stream>>>(weight, B);
    prep_rows<<<NROW, 64, 0, stream>>>(logits, weight, labels, ftl, ftl2, cnt);
    gemm_count<<<NBM * NBN, 256, 0, stream>>>(A, B, ftl, out, cnt);
    apply_k<<<4096, 256, 0, stream>>>(out, ftl, ftl2, labels, cnt);
}

// Round 2
// 961.955 us; speedup vs baseline: 1.1445x; 1.1445x over previous
//
#include <hip/hip_runtime.h>
#include <hip/hip_bf16.h>
#include <hip/hip_fp16.h>
#include <stdint.h>

#define NUM_CLASS 100000
#define CPAD      100096      // padded to multiple of 128
#define EMB       512
#define NROW      1024

#define BM 128
#define BN 128
#define BK 64                 // ushorts of K per tile
#define NBN 782               // CPAD / BN
#define NBM 8                 // NROW / BM

typedef __bf16 bf16x8 __attribute__((ext_vector_type(8)));
typedef float  f32x4  __attribute__((ext_vector_type(4)));

// ---- ws layout (bytes) ----
#define WS_FTL  256
#define WS_FTL2 4352
#define WS_A    8704
#define WS_B    1057280
#define WS_OUTH (WS_B + (size_t)CPAD * EMB * 2)      // fp16 cos, optional

__device__ inline unsigned short f2bf(float x) {
    uint32_t u = __builtin_bit_cast(uint32_t, x);
    uint32_t r = u + 0x7FFFu + ((u >> 16) & 1u);   // RNE, inputs are finite
    return (unsigned short)(r >> 16);
}
__device__ inline unsigned int pack2(float a, float b) {
    return (unsigned int)f2bf(a) | ((unsigned int)f2bf(b) << 16);
}

// async global->LDS, 16 B per lane; LDS dst is wave-uniform base + lane*16
__device__ __forceinline__ void gld16(const unsigned short* g, unsigned short* l) {
    __builtin_amdgcn_global_load_lds(
        (const __attribute__((address_space(1))) unsigned int*)g,
        (__attribute__((address_space(3))) unsigned int*)l,
        16, 0, 0);
}

// ---- normalize logits rows -> bf16 A ----
__global__ __launch_bounds__(256) void prep_a(const float* __restrict__ logits,
                                              unsigned short* __restrict__ A) {
    int wave = threadIdx.x >> 6, lane = threadIdx.x & 63;
    int row = blockIdx.x * 4 + wave;
    const float4* src = (const float4*)(logits + (size_t)row * EMB + lane * 8);
    float4 a = src[0], b = src[1];
    float ss = a.x*a.x + a.y*a.y + a.z*a.z + a.w*a.w
             + b.x*b.x + b.y*b.y + b.z*b.z + b.w*b.w;
    for (int off = 32; off; off >>= 1) ss += __shfl_xor(ss, off, 64);
    float rs = rsqrtf(ss + 1e-12f);
    uint4 o;
    o.x = pack2(a.x*rs, a.y*rs); o.y = pack2(a.z*rs, a.w*rs);
    o.z = pack2(b.x*rs, b.y*rs); o.w = pack2(b.z*rs, b.w*rs);
    *(uint4*)(A + (size_t)row * EMB + lane * 8) = o;
}

// ---- normalize weight rows -> bf16 B (padded rows zero) ----
__global__ __launch_bounds__(256) void prep_b(const float* __restrict__ w,
                                              unsigned short* __restrict__ B) {
    int wave = threadIdx.x >> 6, lane = threadIdx.x & 63;
    int row = blockIdx.x * 4 + wave;
    uint4 o = {0u, 0u, 0u, 0u};
    if (row < NUM_CLASS) {
        const float4* src = (const float4*)(w + (size_t)row * EMB + lane * 8);
        float4 a = src[0], b = src[1];
        float ss = a.x*a.x + a.y*a.y + a.z*a.z + a.w*a.w
                 + b.x*b.x + b.y*b.y + b.z*b.z + b.w*b.w;
        for (int off = 32; off; off >>= 1) ss += __shfl_xor(ss, off, 64);
        float rs = rsqrtf(ss + 1e-12f);
        o.x = pack2(a.x*rs, a.y*rs); o.y = pack2(a.z*rs, a.w*rs);
        o.z = pack2(b.x*rs, b.y*rs); o.w = pack2(b.z*rs, b.w*rs);
    }
    *(uint4*)(B + (size_t)row * EMB + lane * 8) = o;
}

// ---- per-row target cosine + margin thresholds (fp32), zero counter ----
__global__ __launch_bounds__(64) void prep_rows(const float* __restrict__ logits,
                                                const float* __restrict__ w,
                                                const int* __restrict__ labels,
                                                float* __restrict__ ftl,
                                                float* __restrict__ ftl2,
                                                unsigned int* __restrict__ cnt) {
    int row = blockIdx.x, lane = threadIdx.x;
    if (row == 0 && lane == 0) *cnt = 0u;
    int lab = labels[row];
    const float4* lp = (const float4*)(logits + (size_t)row * EMB + lane * 8);
    const float4* wp = (const float4*)(w + (size_t)lab * EMB + lane * 8);
    float4 l0 = lp[0], l1 = lp[1], w0 = wp[0], w1 = wp[1];
    float sl = l0.x*l0.x + l0.y*l0.y + l0.z*l0.z + l0.w*l0.w
             + l1.x*l1.x + l1.y*l1.y + l1.z*l1.z + l1.w*l1.w;
    float sw = w0.x*w0.x + w0.y*w0.y + w0.z*w0.z + w0.w*w0.w
             + w1.x*w1.x + w1.y*w1.y + w1.z*w1.z + w1.w*w1.w;
    float d  = l0.x*w0.x + l0.y*w0.y + l0.z*w0.z + l0.w*w0.w
             + l1.x*w1.x + l1.y*w1.y + l1.z*w1.z + l1.w*w1.w;
    for (int off = 32; off; off >>= 1) {
        sl += __shfl_xor(sl, off, 64);
        sw += __shfl_xor(sw, off, 64);
        d  += __shfl_xor(d,  off, 64);
    }
    if (lane == 0) {
        float tgt = d * rsqrtf(sl + 1e-12f) * rsqrtf(sw + 1e-12f);
        tgt = fminf(1.0f, fmaxf(-1.0f, tgt));
        const float cos_m  = 0.8775825618903728f;
        const float sin_m  = 0.479425538604203f;
        const float theta  = -0.8775825618903728f;
        const float sinmm  = 0.2397127693021015f;
        const float cos_m_ = 0.9800665778412416f;
        const float sin_m_ = 0.19866933079506122f;
        const float sinmm_ = -0.03973386615901225f;
        float st   = sqrtf(fmaxf(0.0f, 1.0f - tgt * tgt));
        float ctm  = tgt * cos_m  - st * sin_m;
        float ctm_ = tgt * cos_m_ - st * sin_m_;
        ftl[row]  = (tgt > theta)    ? ctm  : (tgt - sinmm);
        ftl2[row] = (tgt <= cos_m_)  ? ctm_ : (tgt + sinmm_);
    }
}

// ---- bf16 MFMA GEMM: cos = A * B^T, write clipped cos (f32 or f16), count ----
// 128x128 tile, 4 waves (2x2), acc[4][4]; 32 KB LDS -> high occupancy.
// LDS XOR-swizzle (slot ^= row&7) via pre-swizzled GLOBAL source + matching
// XOR on ds_read (verified: conflicts -> 0 in round 1).
// XCD-bijective remap: 6256 = 8 XCDs * 782; the 8 bm-tiles sharing a B-tile
// run contiguously on one XCD (verified: FETCH 402 -> 101 MB in round 1).
template<int H>
__global__ __launch_bounds__(256) void gemm_count(const unsigned short* __restrict__ A,
                                                  const unsigned short* __restrict__ B,
                                                  const float* __restrict__ ftl,
                                                  float* __restrict__ outf,
                                                  _Float16* __restrict__ outh,
                                                  unsigned int* __restrict__ cnt) {
    __shared__ __align__(16) unsigned short smem[BM * BK + BN * BK];   // 32 KB
    unsigned short* lA = smem;
    unsigned short* lB = smem + BM * BK;
    int tid = threadIdx.x;
    int wave = tid >> 6, lane = tid & 63;
    int wm = wave >> 1, wn = wave & 1;
    int quad = lane >> 4, l16 = lane & 15;
    int sw = l16 & 7;                    // read-side swizzle key (= row&7)

    // XCD-aware bijective remap (grid 6256 = 8 * 782, exact)
    int f  = blockIdx.x;
    int wg = (f & 7) * NBN + (f >> 3);
    int bm = wg & 7;                     // fast: 8 row-tiles share one B-tile
    int bn = wg >> 3;

    f32x4 acc[4][4] = {};

    int srow  = tid >> 3;                // 0..31
    int sslot = tid & 7;                 // linear LDS 16B slot within row
    int sg    = sslot ^ (srow & 7);      // pre-swizzled global slot
    const unsigned short* a_src = A + ((size_t)(bm * BM + srow)) * EMB + sg * 8;
    const unsigned short* b_src = B + ((size_t)(bn * BN + srow)) * EMB + sg * 8;
    unsigned short* a_dst = &lA[tid * 8];   // linear: wave base + lane*16B
    unsigned short* b_dst = &lB[tid * 8];

#pragma unroll 1
    for (int kk = 0; kk < EMB / BK; ++kk) {
        int k0 = kk * BK;
#pragma unroll
        for (int r = 0; r < 4; ++r) {
            gld16(a_src + (size_t)r * 32 * EMB + k0, a_dst + r * 2048);
            gld16(b_src + (size_t)r * 32 * EMB + k0, b_dst + r * 2048);
        }
        __syncthreads();   // drains vmcnt: staged data visible
#pragma unroll
        for (int ks = 0; ks < 2; ++ks) {
            bf16x8 af[4], bfr[4];
#pragma unroll
            for (int i = 0; i < 4; ++i) {
                int ar = wm * 64 + i * 16 + l16;               // ar&7 == sw
                af[i]  = *(const bf16x8*)&lA[ar * BK + (((ks * 4 + quad) ^ sw) << 3)];
                int br = wn * 64 + i * 16 + l16;               // br&7 == sw
                bfr[i] = *(const bf16x8*)&lB[br * BK + (((ks * 4 + quad) ^ sw) << 3)];
            }
#pragma unroll
            for (int i = 0; i < 4; ++i)
#pragma unroll
                for (int j = 0; j < 4; ++j)
                    acc[i][j] = __builtin_amdgcn_mfma_f32_16x16x32_bf16(af[i], bfr[j], acc[i][j], 0, 0, 0);
        }
        __syncthreads();   // all reads done before next overwrite
    }

    int local = 0;
    if (H) {
        // repack through LDS (reuse smem as 128x128 fp16 tile = 32 KB),
        // quad-XOR'd columns -> conflict-free b16 writes; contiguous b128 reads.
        _Float16* tileh = (_Float16*)smem;
#pragma unroll
        for (int i = 0; i < 4; ++i) {
            int row0 = bm * BM + wm * 64 + i * 16 + quad * 4;
            float f0 = ftl[row0], f1 = ftl[row0 + 1], f2 = ftl[row0 + 2], f3 = ftl[row0 + 3];
#pragma unroll
            for (int j = 0; j < 4; ++j) {
                int colg = bn * BN + wn * 64 + j * 16 + l16;
                bool cv  = colg < NUM_CLASS;
                int lc   = (wn * 64 + j * 16 + l16) ^ (quad << 4);
#pragma unroll
                for (int r = 0; r < 4; ++r) {
                    float c = acc[i][j][r];
                    c = fminf(1.0f, fmaxf(-1.0f, c));
                    if (cv) {
                        float fr = (r == 0) ? f0 : (r == 1) ? f1 : (r == 2) ? f2 : f3;
                        local += (c > fr) ? 1 : 0;
                    }
                    int rr = wm * 64 + i * 16 + quad * 4 + r;
                    tileh[rr * BN + lc] = (_Float16)c;
                }
            }
        }
        __syncthreads();
#pragma unroll
        for (int s = 0; s < 8; ++s) {
            int c  = tid + s * 256;            // 0..2047 uint4-chunks
            int rr = c >> 4;                   // 0..127
            int ci = c & 15;
            int kk2 = ((rr >> 2) & 3) << 4;    // quad-of-row XOR key
            int cc = ci * 8;
            uint4 v = *(const uint4*)&tileh[rr * BN + (cc ^ kk2)];
            int gcol = bn * BN + cc;
            if (gcol < NUM_CLASS)
                *(uint4*)&outh[(size_t)(bm * BM + rr) * NUM_CLASS + gcol] = v;
        }
    } else {
#pragma unroll
        for (int i = 0; i < 4; ++i) {
            int row0 = bm * BM + wm * 64 + i * 16 + quad * 4;
            float f0 = ftl[row0], f1 = ftl[row0 + 1], f2 = ftl[row0 + 2], f3 = ftl[row0 + 3];
#pragma unroll
            for (int j = 0; j < 4; ++j) {
                int col = bn * BN + wn * 64 + j * 16 + l16;
                bool cv = col < NUM_CLASS;
#pragma unroll
                for (int r = 0; r < 4; ++r) {
                    float c = acc[i][j][r];
                    c = fminf(1.0f, fmaxf(-1.0f, c));
                    if (cv) {
                        float fr = (r == 0) ? f0 : (r == 1) ? f1 : (r == 2) ? f2 : f3;
                        local += (c > fr) ? 1 : 0;
                        outf[(size_t)(row0 + r) * NUM_CLASS + col] = c;
                    }
                }
            }
        }
    }
    for (int off = 32; off; off >>= 1) local += __shfl_down(local, off, 64);
    if (lane == 0) atomicAdd(cnt, (unsigned int)local);
}

// ---- epilogue from fp16 cos: masks, noise scale, diagonal set, *S ----
__global__ __launch_bounds__(256) void apply_h(float* __restrict__ out,
                                               const _Float16* __restrict__ outh,
                                               const float* __restrict__ ftl,
                                               const float* __restrict__ ftl2,
                                               const int* __restrict__ labels,
                                               const unsigned int* __restrict__ cnt) {
    int row     = blockIdx.x >> 2;
    int quarter = blockIdx.x & 3;
    float h   = (float)(*cnt);
    float msm = ((2900.0f - h) / 2900.0f) * 0.01f;
    float t   = 1.0f - msm / 0.7f;
    float ns  = t * t;
    float fv  = ftl[row], f2v = ftl2[row];
    int   lab = labels[row];
    const uint4* src = (const uint4*)(outh + (size_t)row * NUM_CLASS);
    float4*      dst = (float4*)(out + (size_t)row * NUM_CLASS);
    int cend = (quarter + 1) * 3125;                  // 12500 half-octets per row
    for (int c = quarter * 3125 + (int)threadIdx.x; c < cend; c += 256) {
        union { uint4 u; _Float16 hh[8]; } U;
        U.u = src[c];
        int col = c * 8;
        float r0[8];
#pragma unroll
        for (int q = 0; q < 8; ++q) {
            float cv = (float)U.hh[q];
            float o = (cv > fv) ? cv * 1.2f : cv;      // hard margin: *(T+1)
            if (cv > f2v) o = fmaxf(cv * ns, 1e-30f);  // noise branch overrides
            if (col + q == lab) o = fv;                // diagonal set
            r0[q] = o * 64.0f;                          // *S
        }
        dst[c * 2]     = make_float4(r0[0], r0[1], r0[2], r0[3]);
        dst[c * 2 + 1] = make_float4(r0[4], r0[5], r0[6], r0[7]);
    }
}

// ---- fallback epilogue: in-place f32 ----
__global__ __launch_bounds__(256) void apply_f(float* __restrict__ out,
                                               const float* __restrict__ ftl,
                                               const float* __restrict__ ftl2,
                                               const int* __restrict__ labels,
                                               const unsigned int* __restrict__ cnt) {
    int row     = blockIdx.x >> 2;
    int quarter = blockIdx.x & 3;
    float h   = (float)(*cnt);
    float msm = ((2900.0f - h) / 2900.0f) * 0.01f;
    float t   = 1.0f - msm / 0.7f;
    float ns  = t * t;
    float fv  = ftl[row], f2v = ftl2[row];
    int   lab = labels[row];
    float4* base = (float4*)(out + (size_t)row * NUM_CLASS);
    int c4end = (quarter + 1) * 6250;                 // 25000 float4 per row
    for (int c4 = quarter * 6250 + (int)threadIdx.x; c4 < c4end; c4 += 256) {
        float4 v = base[c4];
        float r[4] = {v.x, v.y, v.z, v.w};
        int col = c4 * 4;
#pragma unroll
        for (int q = 0; q < 4; ++q) {
            float c = r[q];
            float o = (c > fv) ? c * 1.2f : c;
            if (c > f2v) o = fmaxf(c * ns, 1e-30f);
            if (col + q == lab) o = fv;
            r[q] = o * 64.0f;
        }
        base[c4] = make_float4(r[0], r[1], r[2], r[3]);
    }
}

extern "C" void kernel_launch(void* const* d_in, const int* in_sizes, int n_in,
                              void* d_out, int out_size, void* d_ws, size_t ws_size,
                              hipStream_t stream) {
    const float* logits = (const float*)d_in[0];
    const int*   labels = (const int*)d_in[1];
    const float* weight = (const float*)d_in[2];
    char* ws = (char*)d_ws;
    unsigned int*  cnt  = (unsigned int*)ws;
    float*         ftl  = (float*)(ws + WS_FTL);
    float*         ftl2 = (float*)(ws + WS_FTL2);
    unsigned short* A   = (unsigned short*)(ws + WS_A);
    unsigned short* B   = (unsigned short*)(ws + WS_B);
    _Float16*      outh = (_Float16*)(ws + WS_OUTH);
    float* out = (float*)d_out;

    size_t need_h = WS_OUTH + (size_t)NROW * NUM_CLASS * 2;
    bool useH = (ws_size >= need_h);

    prep_a<<<NROW / 4, 256, 0, stream>>>(logits, A);
    prep_b<<<CPAD / 4, 256, 0, stream>>>(weight, B);
    prep_rows<<<NROW, 64, 0, stream>>>(logits, weight, labels, ftl, ftl2, cnt);
    if (useH) {
        gemm_count<1><<<NBM * NBN, 256, 0, stream>>>(A, B, ftl, out, outh, cnt);
        apply_h<<<4096, 256, 0, stream>>>(out, outh, ftl, ftl2, labels, cnt);
    } else {
        gemm_count<0><<<NBM * NBN, 256, 0, stream>>>(A, B, ftl, out, nullptr, cnt);
        apply_f<<<4096, 256, 0, stream>>>(out, ftl, ftl2, labels, cnt);
    }
}

// Round 5
// 830.824 us; speedup vs baseline: 1.3251x; 1.1578x over previous
//
#include <hip/hip_runtime.h>
#include <hip/hip_bf16.h>
#include <hip/hip_fp16.h>
#include <stdint.h>

#define NUM_CLASS 100000
#define CPAD      100096      // padded to multiple of 128
#define EMB       512
#define NROW      1024

#define BM 128
#define BN 128
#define BK 64                 // ushorts of K per tile
#define NBN 782               // CPAD / BN
#define NBM 8                 // NROW / BM
#define BUF ((BM + BN) * BK)  // one buffer in ushorts (32 KB)

typedef __bf16 bf16x8 __attribute__((ext_vector_type(8)));
typedef float  f32x4  __attribute__((ext_vector_type(4)));

// ---- ws layout (bytes) ----
#define WS_FTL  256
#define WS_FTL2 4352
#define WS_A    8704
#define WS_B    1057280
#define WS_OUTH (WS_B + (size_t)CPAD * EMB * 2)      // fp16 cos, optional

__device__ inline unsigned short f2bf(float x) {
    uint32_t u = __builtin_bit_cast(uint32_t, x);
    uint32_t r = u + 0x7FFFu + ((u >> 16) & 1u);   // RNE, inputs are finite
    return (unsigned short)(r >> 16);
}
__device__ inline unsigned int pack2(float a, float b) {
    return (unsigned int)f2bf(a) | ((unsigned int)f2bf(b) << 16);
}

// nt store of 4 floats through an elementary vector type (float4 class is
// rejected by __builtin_nontemporal_store)
__device__ __forceinline__ void nt_store4(float* p, float a, float b, float c, float d) {
    f32x4 v = {a, b, c, d};
    __builtin_nontemporal_store(v, (f32x4*)p);
}

// async global->LDS, 16 B per lane; LDS dst is wave-uniform base + lane*16
__device__ __forceinline__ void gld16(const unsigned short* g, unsigned short* l) {
    __builtin_amdgcn_global_load_lds(
        (const __attribute__((address_space(1))) unsigned int*)g,
        (__attribute__((address_space(3))) unsigned int*)l,
        16, 0, 0);
}

// ---- normalize logits rows -> bf16 A ----
__global__ __launch_bounds__(256) void prep_a(const float* __restrict__ logits,
                                              unsigned short* __restrict__ A) {
    int wave = threadIdx.x >> 6, lane = threadIdx.x & 63;
    int row = blockIdx.x * 4 + wave;
    const float4* src = (const float4*)(logits + (size_t)row * EMB + lane * 8);
    float4 a = src[0], b = src[1];
    float ss = a.x*a.x + a.y*a.y + a.z*a.z + a.w*a.w
             + b.x*b.x + b.y*b.y + b.z*b.z + b.w*b.w;
    for (int off = 32; off; off >>= 1) ss += __shfl_xor(ss, off, 64);
    float rs = rsqrtf(ss + 1e-12f);
    uint4 o;
    o.x = pack2(a.x*rs, a.y*rs); o.y = pack2(a.z*rs, a.w*rs);
    o.z = pack2(b.x*rs, b.y*rs); o.w = pack2(b.z*rs, b.w*rs);
    *(uint4*)(A + (size_t)row * EMB + lane * 8) = o;
}

// ---- normalize weight rows -> bf16 B (padded rows zero) ----
__global__ __launch_bounds__(256) void prep_b(const float* __restrict__ w,
                                              unsigned short* __restrict__ B) {
    int wave = threadIdx.x >> 6, lane = threadIdx.x & 63;
    int row = blockIdx.x * 4 + wave;
    uint4 o = {0u, 0u, 0u, 0u};
    if (row < NUM_CLASS) {
        const float4* src = (const float4*)(w + (size_t)row * EMB + lane * 8);
        float4 a = src[0], b = src[1];
        float ss = a.x*a.x + a.y*a.y + a.z*a.z + a.w*a.w
                 + b.x*b.x + b.y*b.y + b.z*b.z + b.w*b.w;
        for (int off = 32; off; off >>= 1) ss += __shfl_xor(ss, off, 64);
        float rs = rsqrtf(ss + 1e-12f);
        o.x = pack2(a.x*rs, a.y*rs); o.y = pack2(a.z*rs, a.w*rs);
        o.z = pack2(b.x*rs, b.y*rs); o.w = pack2(b.z*rs, b.w*rs);
    }
    *(uint4*)(B + (size_t)row * EMB + lane * 8) = o;
}

// ---- per-row target cosine + margin thresholds (fp32), zero counter ----
__global__ __launch_bounds__(64) void prep_rows(const float* __restrict__ logits,
                                                const float* __restrict__ w,
                                                const int* __restrict__ labels,
                                                float* __restrict__ ftl,
                                                float* __restrict__ ftl2,
                                                unsigned int* __restrict__ cnt) {
    int row = blockIdx.x, lane = threadIdx.x;
    if (row == 0 && lane == 0) *cnt = 0u;
    int lab = labels[row];
    const float4* lp = (const float4*)(logits + (size_t)row * EMB + lane * 8);
    const float4* wp = (const float4*)(w + (size_t)lab * EMB + lane * 8);
    float4 l0 = lp[0], l1 = lp[1], w0 = wp[0], w1 = wp[1];
    float sl = l0.x*l0.x + l0.y*l0.y + l0.z*l0.z + l0.w*l0.w
             + l1.x*l1.x + l1.y*l1.y + l1.z*l1.z + l1.w*l1.w;
    float sw = w0.x*w0.x + w0.y*w0.y + w0.z*w0.z + w0.w*w0.w
             + w1.x*w1.x + w1.y*w1.y + w1.z*w1.z + w1.w*w1.w;
    float d  = l0.x*w0.x + l0.y*w0.y + l0.z*w0.z + l0.w*w0.w
             + l1.x*w1.x + l1.y*w1.y + l1.z*w1.z + l1.w*w1.w;
    for (int off = 32; off; off >>= 1) {
        sl += __shfl_xor(sl, off, 64);
        sw += __shfl_xor(sw, off, 64);
        d  += __shfl_xor(d,  off, 64);
    }
    if (lane == 0) {
        float tgt = d * rsqrtf(sl + 1e-12f) * rsqrtf(sw + 1e-12f);
        tgt = fminf(1.0f, fmaxf(-1.0f, tgt));
        const float cos_m  = 0.8775825618903728f;
        const float sin_m  = 0.479425538604203f;
        const float theta  = -0.8775825618903728f;
        const float sinmm  = 0.2397127693021015f;
        const float cos_m_ = 0.9800665778412416f;
        const float sin_m_ = 0.19866933079506122f;
        const float sinmm_ = -0.03973386615901225f;
        float st   = sqrtf(fmaxf(0.0f, 1.0f - tgt * tgt));
        float ctm  = tgt * cos_m  - st * sin_m;
        float ctm_ = tgt * cos_m_ - st * sin_m_;
        ftl[row]  = (tgt > theta)    ? ctm  : (tgt - sinmm);
        ftl2[row] = (tgt <= cos_m_)  ? ctm_ : (tgt + sinmm_);
    }
}

// ---- bf16 MFMA GEMM: cos = A * B^T, write clipped cos (f32 or f16), count ----
// 128x128 tile, 4 waves (2x2), acc[4][4].
// DOUBLE-BUFFERED LDS (2 x 32 KB = 64 KB), prefetch-before-compute:
//   prologue: stage(buf0); barrier
//   iter kk : stage(buf[kk+1]) ; ds_read+MFMA(buf[kk]) ; barrier
// Single LDS base + runtime cur*BUF offset (pointer ARRAYS of LDS addrs
// fail to compile: addrspacecast in static initializer).
// LDS XOR-swizzle via pre-swizzled global source (verified: conflicts=0).
// XCD-bijective remap (verified: FETCH 402 -> 62 MB).
template<int H>
__global__ __launch_bounds__(256) void gemm_count(const unsigned short* __restrict__ A,
                                                  const unsigned short* __restrict__ B,
                                                  const float* __restrict__ ftl,
                                                  float* __restrict__ outf,
                                                  _Float16* __restrict__ outh,
                                                  unsigned int* __restrict__ cnt) {
    __shared__ __align__(16) unsigned short smem[2 * BUF];   // 64 KB
    __shared__ unsigned int s_blk;
    unsigned short* lA = smem;            // + cur*BUF
    unsigned short* lB = smem + BM * BK;  // + cur*BUF
    int tid = threadIdx.x;
    int wave = tid >> 6, lane = tid & 63;
    int wm = wave >> 1, wn = wave & 1;
    int quad = lane >> 4, l16 = lane & 15;
    int sw = l16 & 7;                    // read-side swizzle key (= row&7)

    // XCD-aware bijective remap (grid 6256 = 8 * 782, exact)
    int f  = blockIdx.x;
    int wg = (f & 7) * NBN + (f >> 3);
    int bm = wg & 7;                     // fast: 8 row-tiles share one B-tile
    int bn = wg >> 3;

    f32x4 acc[4][4] = {};

    int srow  = tid >> 3;                // 0..31
    int sslot = tid & 7;                 // linear LDS 16B slot within row
    int sg    = sslot ^ (srow & 7);      // pre-swizzled global slot
    const unsigned short* a_src = A + ((size_t)(bm * BM + srow)) * EMB + sg * 8;
    const unsigned short* b_src = B + ((size_t)(bn * BN + srow)) * EMB + sg * 8;

    if (tid == 0) s_blk = 0u;

    // prologue: stage K-tile 0 into buffer 0
#pragma unroll
    for (int r = 0; r < 4; ++r) {
        gld16(a_src + (size_t)r * 32 * EMB, &lA[tid * 8 + r * 2048]);
        gld16(b_src + (size_t)r * 32 * EMB, &lB[tid * 8 + r * 2048]);
    }
    __syncthreads();   // drains vmcnt(0): buf0 ready (also covers s_blk init)

#pragma unroll 1
    for (int kk = 0; kk < EMB / BK; ++kk) {
        int co = (kk & 1) * BUF;         // current buffer offset
        int no = co ^ BUF;               // next buffer offset
        if (kk < EMB / BK - 1) {
            int k0 = (kk + 1) * BK;
#pragma unroll
            for (int r = 0; r < 4; ++r) {
                gld16(a_src + (size_t)r * 32 * EMB + k0, &lA[no + tid * 8 + r * 2048]);
                gld16(b_src + (size_t)r * 32 * EMB + k0, &lB[no + tid * 8 + r * 2048]);
            }
        }
#pragma unroll
        for (int ks = 0; ks < 2; ++ks) {
            bf16x8 af[4], bfr[4];
#pragma unroll
            for (int i = 0; i < 4; ++i) {
                int ar = wm * 64 + i * 16 + l16;               // ar&7 == sw
                af[i]  = *(const bf16x8*)&lA[co + ar * BK + (((ks * 4 + quad) ^ sw) << 3)];
                int br = wn * 64 + i * 16 + l16;               // br&7 == sw
                bfr[i] = *(const bf16x8*)&lB[co + br * BK + (((ks * 4 + quad) ^ sw) << 3)];
            }
#pragma unroll
            for (int i = 0; i < 4; ++i)
#pragma unroll
                for (int j = 0; j < 4; ++j)
                    acc[i][j] = __builtin_amdgcn_mfma_f32_16x16x32_bf16(af[i], bfr[j], acc[i][j], 0, 0, 0);
        }
        __syncthreads();   // drains prefetch; all reads of buf[cur] done
    }

    int local = 0;
    if (H) {
        // repack through LDS (reuse smem as 128x128 fp16 tile = 32 KB),
        // quad-XOR'd columns -> conflict-free b16 writes; contiguous b128 reads.
        _Float16* tileh = (_Float16*)smem;
#pragma unroll
        for (int i = 0; i < 4; ++i) {
            int row0 = bm * BM + wm * 64 + i * 16 + quad * 4;
            float f0 = ftl[row0], f1 = ftl[row0 + 1], f2 = ftl[row0 + 2], f3 = ftl[row0 + 3];
#pragma unroll
            for (int j = 0; j < 4; ++j) {
                int colg = bn * BN + wn * 64 + j * 16 + l16;
                bool cv  = colg < NUM_CLASS;
                int lc   = (wn * 64 + j * 16 + l16) ^ (quad << 4);
#pragma unroll
                for (int r = 0; r < 4; ++r) {
                    float c = acc[i][j][r];
                    c = fminf(1.0f, fmaxf(-1.0f, c));
                    if (cv) {
                        float fr = (r == 0) ? f0 : (r == 1) ? f1 : (r == 2) ? f2 : f3;
                        local += (c > fr) ? 1 : 0;
                    }
                    int rr = wm * 64 + i * 16 + quad * 4 + r;
                    tileh[rr * BN + lc] = (_Float16)c;
                }
            }
        }
        for (int off = 32; off; off >>= 1) local += __shfl_down(local, off, 64);
        if (lane == 0) atomicAdd(&s_blk, (unsigned int)local);
        __syncthreads();
        if (tid == 0 && s_blk) atomicAdd(cnt, s_blk);
#pragma unroll
        for (int s = 0; s < 8; ++s) {
            int c  = tid + s * 256;            // 0..2047 uint4-chunks
            int rr = c >> 4;                   // 0..127
            int ci = c & 15;
            int kk2 = ((rr >> 2) & 3) << 4;    // quad-of-row XOR key
            int cc = ci * 8;
            uint4 v = *(const uint4*)&tileh[rr * BN + (cc ^ kk2)];
            int gcol = bn * BN + cc;
            if (gcol < NUM_CLASS)
                *(uint4*)&outh[(size_t)(bm * BM + rr) * NUM_CLASS + gcol] = v;
        }
    } else {
#pragma unroll
        for (int i = 0; i < 4; ++i) {
            int row0 = bm * BM + wm * 64 + i * 16 + quad * 4;
            float f0 = ftl[row0], f1 = ftl[row0 + 1], f2 = ftl[row0 + 2], f3 = ftl[row0 + 3];
#pragma unroll
            for (int j = 0; j < 4; ++j) {
                int col = bn * BN + wn * 64 + j * 16 + l16;
                bool cv = col < NUM_CLASS;
#pragma unroll
                for (int r = 0; r < 4; ++r) {
                    float c = acc[i][j][r];
                    c = fminf(1.0f, fmaxf(-1.0f, c));
                    if (cv) {
                        float fr = (r == 0) ? f0 : (r == 1) ? f1 : (r == 2) ? f2 : f3;
                        local += (c > fr) ? 1 : 0;
                        outf[(size_t)(row0 + r) * NUM_CLASS + col] = c;
                    }
                }
            }
        }
        for (int off = 32; off; off >>= 1) local += __shfl_down(local, off, 64);
        if (lane == 0) atomicAdd(&s_blk, (unsigned int)local);
        __syncthreads();
        if (tid == 0 && s_blk) atomicAdd(cnt, s_blk);
    }
}

// ---- epilogue from fp16 cos: masks, noise scale, diagonal set, *S ----
__global__ __launch_bounds__(256) void apply_h(float* __restrict__ out,
                                               const _Float16* __restrict__ outh,
                                               const float* __restrict__ ftl,
                                               const float* __restrict__ ftl2,
                                               const int* __restrict__ labels,
                                               const unsigned int* __restrict__ cnt) {
    int row     = blockIdx.x >> 2;
    int quarter = blockIdx.x & 3;
    float h   = (float)(*cnt);
    float msm = ((2900.0f - h) / 2900.0f) * 0.01f;
    float t   = 1.0f - msm / 0.7f;
    float ns  = t * t;
    float fv  = ftl[row], f2v = ftl2[row];
    int   lab = labels[row];
    const uint4* src = (const uint4*)(outh + (size_t)row * NUM_CLASS);
    float*       dst = out + (size_t)row * NUM_CLASS;
    int cend = (quarter + 1) * 3125;                  // 12500 half-octets per row
    for (int c = quarter * 3125 + (int)threadIdx.x; c < cend; c += 256) {
        union { uint4 u; _Float16 hh[8]; } U;
        U.u = src[c];
        int col = c * 8;
        float r0[8];
#pragma unroll
        for (int q = 0; q < 8; ++q) {
            float cv = (float)U.hh[q];
            float o = (cv > fv) ? cv * 1.2f : cv;      // hard margin: *(T+1)
            if (cv > f2v) o = fmaxf(cv * ns, 1e-30f);  // noise branch overrides
            if (col + q == lab) o = fv;                // diagonal set
            r0[q] = o * 64.0f;                          // *S
        }
        nt_store4(dst + col,     r0[0], r0[1], r0[2], r0[3]);
        nt_store4(dst + col + 4, r0[4], r0[5], r0[6], r0[7]);
    }
}

// ---- fallback epilogue: in-place f32 ----
__global__ __launch_bounds__(256) void apply_f(float* __restrict__ out,
                                               const float* __restrict__ ftl,
                                               const float* __restrict__ ftl2,
                                               const int* __restrict__ labels,
                                               const unsigned int* __restrict__ cnt) {
    int row     = blockIdx.x >> 2;
    int quarter = blockIdx.x & 3;
    float h   = (float)(*cnt);
    float msm = ((2900.0f - h) / 2900.0f) * 0.01f;
    float t   = 1.0f - msm / 0.7f;
    float ns  = t * t;
    float fv  = ftl[row], f2v = ftl2[row];
    int   lab = labels[row];
    float* base = out + (size_t)row * NUM_CLASS;
    int c4end = (quarter + 1) * 6250;                 // 25000 float4 per row
    for (int c4 = quarter * 6250 + (int)threadIdx.x; c4 < c4end; c4 += 256) {
        float4 v = *(const float4*)(base + c4 * 4);
        float r[4] = {v.x, v.y, v.z, v.w};
        int col = c4 * 4;
#pragma unroll
        for (int q = 0; q < 4; ++q) {
            float c = r[q];
            float o = (c > fv) ? c * 1.2f : c;
            if (c > f2v) o = fmaxf(c * ns, 1e-30f);
            if (col + q == lab) o = fv;
            r[q] = o * 64.0f;
        }
        nt_store4(base + col, r[0], r[1], r[2], r[3]);
    }
}

extern "C" void kernel_launch(void* const* d_in, const int* in_sizes, int n_in,
                              void* d_out, int out_size, void* d_ws, size_t ws_size,
                              hipStream_t stream) {
    const float* logits = (const float*)d_in[0];
    const int*   labels = (const int*)d_in[1];
    const float* weight = (const float*)d_in[2];
    char* ws = (char*)d_ws;
    unsigned int*  cnt  = (unsigned int*)ws;
    float*         ftl  = (float*)(ws + WS_FTL);
    float*         ftl2 = (float*)(ws + WS_FTL2);
    unsigned short* A   = (unsigned short*)(ws + WS_A);
    unsigned short* B   = (unsigned short*)(ws + WS_B);
    _Float16*      outh = (_Float16*)(ws + WS_OUTH);
    float* out = (float*)d_out;

    size_t need_h = WS_OUTH + (size_t)NROW * NUM_CLASS * 2;
    bool useH = (ws_size >= need_h);

    prep_a<<<NROW / 4, 256, 0, stream>>>(logits, A);
    prep_b<<<CPAD / 4, 256, 0, stream>>>(weight, B);
    prep_rows<<<NROW, 64, 0, stream>>>(logits, weight, labels, ftl, ftl2, cnt);
    if (useH) {
        gemm_count<1><<<NBM * NBN, 256, 0, stream>>>(A, B, ftl, out, outh, cnt);
        apply_h<<<4096, 256, 0, stream>>>(out, outh, ftl, ftl2, labels, cnt);
    } else {
        gemm_count<0><<<NBM * NBN, 256, 0, stream>>>(A, B, ftl, out, nullptr, cnt);
        apply_f<<<4096, 256, 0, stream>>>(out, ftl, ftl2, labels, cnt);
    }
}